// Round 6
// baseline (992.909 us; speedup 1.0000x reference)
//
#include <hip/hip_runtime.h>

typedef __bf16 bf16x8 __attribute__((ext_vector_type(8)));
typedef float  v16f   __attribute__((ext_vector_type(16)));
typedef unsigned short ushort_t;

#define HH 768
#define WW 768
#define CH 3
#define KS 24
#define HC 745
#define WC 745
#define NP 256
#define XH 384
#define XW 384

#define NBX 24            // ceil(745/32)
#define NBY 187           // ceil(745/4)
#define NBLK (NBX*NBY)    // 4488
#define BROWS 4
#define BCOLS 32
#define NSTEP 54          // K=1728 in 32-wide slices
#define NCAND 8

// async global->LDS DMA; LDS dest = wave-uniform base + lane*size (global addr is per-lane)
__device__ __forceinline__ void gload16(const ushort_t* g, ushort_t* l) {
    __builtin_amdgcn_global_load_lds(
        (const __attribute__((address_space(1))) unsigned int*)(const void*)g,
        (__attribute__((address_space(3))) unsigned int*)(void*)l, 16, 0, 0);
}
__device__ __forceinline__ void gload4(const ushort_t* g, ushort_t* l) {
    __builtin_amdgcn_global_load_lds(
        (const __attribute__((address_space(1))) unsigned int*)(const void*)g,
        (__attribute__((address_space(3))) unsigned int*)(void*)l, 4, 0, 0);
}
__device__ __forceinline__ ushort_t f2bf(float f) {
    union { __bf16 h; ushort_t u; } cv; cv.h = (__bf16)f; return cv.u;
}
__device__ __forceinline__ float bf2f(ushort_t u) {
    union { unsigned u; float f; } cv; cv.u = ((unsigned)u) << 16; return cv.f;
}

// -------------------- prep kernels --------------------

__global__ void k_colsum(const float* __restrict__ y, float* __restrict__ ksum,
                         float* __restrict__ ksum2) {
    int idx = blockIdx.x * 256 + threadIdx.x;
    if (idx >= HH * WW) return;
    float a = y[idx], b = y[idx + HH * WW], c = y[idx + 2 * HH * WW];
    ksum[idx]  = a + b + c;
    ksum2[idx] = a * a + b * b + c * c;
}

__global__ void k_hsum(const float* __restrict__ ksum, const float* __restrict__ ksum2,
                       float* __restrict__ h1, float* __restrict__ h2) {
    int idx = blockIdx.x * 256 + threadIdx.x;
    if (idx >= HH * WC) return;
    int h = idx / WC, w = idx % WC;
    const float* r  = ksum  + h * WW + w;
    const float* r2 = ksum2 + h * WW + w;
    float s = 0.f, s2 = 0.f;
    #pragma unroll
    for (int j = 0; j < KS; j++) { s += r[j]; s2 += r2[j]; }
    h1[idx] = s; h2[idx] = s2;
}

// bf16 maps are ONLY used for the approximate pre-screen; k_rescore recomputes exactly.
__global__ void k_vsum(const float* __restrict__ h1, const float* __restrict__ h2,
                       ushort_t* __restrict__ s1m, ushort_t* __restrict__ ivm) {
    int idx = blockIdx.x * 256 + threadIdx.x;
    if (idx >= HC * WC) return;
    int r = idx / WC, w = idx % WC;
    float s = 0.f, s2 = 0.f;
    #pragma unroll
    for (int i = 0; i < KS; i++) { s += h1[(r + i) * WC + w]; s2 += h2[(r + i) * WC + w]; }
    float d2 = s2 - s * s * (1.0f / 576.0f);
    s1m[idx] = f2bf(s);
    ivm[idx] = f2bf(rsqrtf(fmaxf(d2, 1e-20f)));
}

__global__ void k_meanx(const float* __restrict__ x, float* __restrict__ mx) {
    int p = blockIdx.x;
    int pr = p >> 4, pc = p & 15;
    float s = 0.f;
    for (int e = threadIdx.x; e < CH * KS * KS; e += 256) {
        int c = e / (KS * KS); int rem = e % (KS * KS);
        int i = rem / KS, j = rem % KS;
        s += x[(c * XH + pr * KS + i) * XW + pc * KS + j];
    }
    __shared__ float red[256];
    red[threadIdx.x] = s; __syncthreads();
    for (int st = 128; st > 0; st >>= 1) {
        if (threadIdx.x < st) red[threadIdx.x] += red[threadIdx.x + st];
        __syncthreads();
    }
    if (threadIdx.x == 0) mx[p] = red[0] * (1.0f / 1728.0f);
}

__global__ void k_bmat(const float* __restrict__ x, ushort_t* __restrict__ bm) {
    int p = blockIdx.x; int pr = p >> 4, pc = p & 15;
    for (int e = threadIdx.x; e < CH * KS * KS; e += 256) {
        int c = e / (KS * KS), rem = e % (KS * KS), i = rem / KS, j = rem % KS;
        bm[p * 1728 + e] = f2bf(x[(c * XH + pr * KS + i) * XW + pc * KS + j]);
    }
}

// 2 column-shifted bf16 copies: y2[S][c][r][t] = bf16(ydec[c][r][t+S]), S in {0,1}, 0-pad OOB.
__global__ void k_y2(const float* __restrict__ yd, ushort_t* __restrict__ y2) {
    int idx = blockIdx.x * 256 + threadIdx.x;
    if (idx >= 2 * 3 * HH * (WW / 8)) return;
    int t8 = idx % (WW / 8); int rem = idx / (WW / 8);
    int r = rem % HH; rem /= HH;
    int c = rem % 3; int S = rem / 3;
    const float* src = yd + (c * HH + r) * WW;
    union { ushort_t u[8]; uint4 v; } o;
    #pragma unroll
    for (int q = 0; q < 8; q++) {
        int t = t8 * 8 + q + S;
        o.u[q] = f2bf(t < WW ? src[t] : 0.f);
    }
    ((uint4*)(y2 + ((size_t)(S * 3 + c) * HH + r) * WW))[t8] = o.v;
}

// -------------------- main MFMA correlation kernel --------------------
// 512 thr, tile = 128 pos (4x32) x 256 patches; wave tile 64x64 of mfma_f32_32x32x16_bf16.
// LDS tiles are SLOT-MAJOR [k-octet-plane][row][8] so frag reads are 16B/lane at 16B
// stride -> all 32 banks, conflict-free (R5's 64B row pitch = 16-bank aliasing = 2x LDS cost).

__global__ __launch_bounds__(512, 4) void k_corr(
    const ushort_t* __restrict__ y2, const ushort_t* __restrict__ bmat,
    const ushort_t* __restrict__ s1m, const ushort_t* __restrict__ ivm,
    const float* __restrict__ mx, ushort_t* __restrict__ ps16)
{
    __shared__ __align__(16) ushort_t Ab[4 * 128 * 8];   // 8KB  [oct-plane][pos][8]
    __shared__ __align__(16) ushort_t Bb[4 * 256 * 8];   // 16KB [oct-plane][pat][8]
    __shared__ float red[NP * 2];

    const int tid = threadIdx.x;
    const int wave = tid >> 6, lane = tid & 63;
    const int bx = blockIdx.x % NBX, by = blockIdx.x / NBX;
    const int r0 = by * BROWS, w0 = bx * BCOLS;

    // A staging (4x gload4/slice): round u fills plane u; dest byte = u*2048 + 4*tid
    //  -> thread covers (pos = tid>>2, dword = tid&3), i.e. k-pair (dwsub*2, dwsub*2+1).
    const int apos = tid >> 2, dwsub = tid & 3;
    const int prow = apos >> 5, pcol = apos & 31;
    const int Sp = pcol & 1;                       // column parity -> shifted copy (4B align)
    const ushort_t* ybase = y2 + (size_t)(Sp * 3) * HH * WW;
    const int colbase = w0 + pcol - Sp + dwsub * 2;   // + j0 per round (stays even)
    const int rowpt = r0 + prow;                      // + i per round
    ushort_t* aldsw = Ab + wave * 128;                // + u*1024 ushorts per round

    // B staging (2x gload16/slice): chunk q -> plane q*2+(wave>>2), pat (wave&3)*64+lane
    const int bpat = (wave & 3) * 64 + lane;
    const int oct0 = wave >> 2;
    const ushort_t* gbp = bmat + bpat * 1728 + oct0 * 8;
    ushort_t* blds0 = Bb + wave * 512;               // byte w*1024 (+lane*16)
    ushort_t* blds1 = Bb + 4096 + wave * 512;        // byte 8192 + w*1024

    const int l31 = lane & 31, h = lane >> 5;
    const int wm = wave >> 2, wn = wave & 3;

    v16f acc[2][2];
    #pragma unroll
    for (int a = 0; a < 2; a++)
        #pragma unroll
        for (int b = 0; b < 2; b++)
            #pragma unroll
            for (int r = 0; r < 16; r++) acc[a][b][r] = 0.f;

    int c = 0, ii = 0, j0 = 0;   // octet cursor (wave-uniform), advances 4x per slice

    #pragma unroll 1
    for (int s = 0; s < NSTEP; s++) {
        __syncthreads();                       // old tiles fully consumed
        #pragma unroll
        for (int u = 0; u < 4; u++) {          // stage A plane u (octet s*4+u)
            int grow = rowpt + ii; grow = grow < HH ? grow : HH - 1;        // clamp: invalid pos only
            int gcol = colbase + j0; gcol = gcol < WW - 1 ? gcol : WW - 2;  // clamp keeps 4B align
            gload4(ybase + ((size_t)c * HH + grow) * WW + gcol, aldsw + u * 1024);
            j0 += 8;
            if (j0 == KS) { j0 = 0; ii++; if (ii == KS) { ii = 0; c++; } }
        }
        gload16(gbp + s * 32,      blds0);     // plane oct0   (octet s*4+oct0)
        gload16(gbp + s * 32 + 16, blds1);     // plane oct0+2 (octet s*4+oct0+2)
        __syncthreads();                       // staging landed (vmcnt drained at barrier)

        bf16x8 af[2][2], bfr[2][2];
        #pragma unroll
        for (int mt = 0; mt < 2; mt++)
            #pragma unroll
            for (int ks = 0; ks < 2; ks++)
                af[mt][ks] = *(const bf16x8*)(Ab + (ks * 2 + h) * 1024 + (wm * 64 + mt * 32 + l31) * 8);
        #pragma unroll
        for (int nt = 0; nt < 2; nt++)
            #pragma unroll
            for (int ks = 0; ks < 2; ks++)
                bfr[nt][ks] = *(const bf16x8*)(Bb + (ks * 2 + h) * 2048 + (wn * 64 + nt * 32 + l31) * 8);
        #pragma unroll
        for (int ks = 0; ks < 2; ks++)
            #pragma unroll
            for (int mt = 0; mt < 2; mt++)
                #pragma unroll
                for (int nt = 0; nt < 2; nt++)
                    acc[mt][nt] = __builtin_amdgcn_mfma_f32_32x32x16_bf16(
                        af[mt][ks], bfr[nt][ks], acc[mt][nt], 0, 0, 0);
    }

    // epilogue: approx score + per-(patch, block) max
    float mx0 = mx[wn * 64 + l31];
    float mx1 = mx[wn * 64 + 32 + l31];
    float best0 = -1e30f, best1 = -1e30f;
    #pragma unroll
    for (int mt = 0; mt < 2; mt++) {
        #pragma unroll
        for (int r = 0; r < 16; r++) {
            int row32 = (r & 3) + 8 * (r >> 2) + 4 * h;   // 32x32 C/D row (m74/m101)
            int posid = wm * 64 + mt * 32 + row32;
            int rg = r0 + (posid >> 5), wg = w0 + (posid & 31);
            bool valid = (rg < HC) && (wg < WC);
            int pos = rg * WC + wg;
            float S1 = valid ? bf2f(s1m[pos]) : 0.f;
            float iv = valid ? bf2f(ivm[pos]) : 0.f;
            float sc0 = valid ? (acc[mt][0][r] - mx0 * S1) * iv : -1e30f;
            float sc1 = valid ? (acc[mt][1][r] - mx1 * S1) * iv : -1e30f;
            best0 = fmaxf(best0, sc0);
            best1 = fmaxf(best1, sc1);
        }
    }
    best0 = fmaxf(best0, __shfl_xor(best0, 32));
    best1 = fmaxf(best1, __shfl_xor(best1, 32));
    __syncthreads();
    if (h == 0) {
        red[(wn * 64 + l31) * 2 + wm]      = best0;
        red[(wn * 64 + 32 + l31) * 2 + wm] = best1;
    }
    __syncthreads();
    if (tid < NP) ps16[blockIdx.x * NP + tid] = f2bf(fmaxf(red[tid * 2], red[tid * 2 + 1]));
}

// -------------------- per-patch top-8 blocks --------------------

__global__ void k_select(const ushort_t* __restrict__ ps16, int* __restrict__ cand) {
    int p = blockIdx.x, tid = threadIdx.x;
    __shared__ float ls[NBLK];
    __shared__ float rs[256];
    __shared__ int   ri[256];
    for (int e = tid; e < NBLK; e += 256) ls[e] = bf2f(ps16[e * NP + p]);
    __syncthreads();
    for (int round = 0; round < NCAND; round++) {
        float bs = -1e38f; int bi = 0;
        for (int e = tid; e < NBLK; e += 256) if (ls[e] > bs) { bs = ls[e]; bi = e; }
        rs[tid] = bs; ri[tid] = bi; __syncthreads();
        for (int st = 128; st > 0; st >>= 1) {
            if (tid < st && rs[tid + st] > rs[tid]) { rs[tid] = rs[tid + st]; ri[tid] = ri[tid + st]; }
            __syncthreads();
        }
        int win = ri[0];
        if (tid == 0) cand[p * NCAND + round] = win;
        if (tid == (win & 255)) ls[win] = -1e38f;
        __syncthreads();
    }
}

// -------------------- exact fp32 rescore (recomputes window sums) + gather --------------------

__global__ void k_rescore(const int* __restrict__ cand, const float* __restrict__ xdec,
                          const float* __restrict__ ydec, const float* __restrict__ mx,
                          const float* __restrict__ yfull, float* __restrict__ out) {
    int p = blockIdx.x, tid = threadIdx.x;
    int pr = p >> 4, pc = p & 15;
    float mxp = mx[p];
    float best = -1e30f; int bpos = 0x7FFFFFFF;
    #pragma unroll 1
    for (int cdp = 0; cdp < 4; cdp++) {
        int cd = cdp * 2 + (tid >> 7);
        int blk = cand[p * NCAND + cd];
        int r0 = (blk / NBX) * BROWS, w0 = (blk % NBX) * BCOLS;
        int pi = tid & 127;
        int rg = r0 + (pi >> 5), wg = w0 + (pi & 31);
        if (rg < HC && wg < WC) {
            float sxy = 0.f, sy = 0.f, sy2 = 0.f;
            for (int c = 0; c < CH; c++) {
                #pragma unroll 1
                for (int i = 0; i < KS; i++) {
                    const float* yr = ydec + (c * HH + rg + i) * WW + wg;
                    const float* xr = xdec + (c * XH + pr * KS + i) * XW + pc * KS;
                    #pragma unroll
                    for (int j = 0; j < KS; j++) {
                        float yv = yr[j];
                        sxy = fmaf(yv, xr[j], sxy);
                        sy += yv;
                        sy2 = fmaf(yv, yv, sy2);
                    }
                }
            }
            float d2 = sy2 - sy * sy * (1.0f / 576.0f);
            int pos = rg * WC + wg;
            float sc = (sxy - mxp * sy) * rsqrtf(fmaxf(d2, 1e-20f));
            if (sc > best || (sc == best && pos < bpos)) { best = sc; bpos = pos; }
        }
    }
    __shared__ float rs[256];
    __shared__ int   ri[256];
    rs[tid] = best; ri[tid] = bpos; __syncthreads();
    for (int st = 128; st > 0; st >>= 1) {
        if (tid < st) {
            if (rs[tid + st] > rs[tid] || (rs[tid + st] == rs[tid] && ri[tid + st] < ri[tid])) {
                rs[tid] = rs[tid + st]; ri[tid] = ri[tid + st];
            }
        }
        __syncthreads();
    }
    int bestpos = ri[0];
    int row = bestpos / WC, col = bestpos % WC;
    for (int e = tid; e < CH * KS * KS; e += 256) {
        int c = e / (KS * KS), rem = e % (KS * KS), i = rem / KS, j = rem % KS;
        out[p * CH * KS * KS + e] = yfull[(c * HH + row + i) * WW + col + j];
    }
}

// -------------------- launch --------------------
// Total ws: 3,124,512 floats = 11.9 MB (R5's proven-safe footprint; R4's 37.8 MB overflowed).

extern "C" void kernel_launch(void* const* d_in, const int* in_sizes, int n_in,
                              void* d_out, int out_size, void* d_ws, size_t ws_size,
                              hipStream_t stream) {
    const float* xdec = (const float*)d_in[0];   // (1,3,384,384)
    const float* ydec = (const float*)d_in[1];   // (1,3,768,768)
    const float* y    = (const float*)d_in[2];   // (1,3,768,768)
    float* out = (float*)d_out;                  // (256,3,24,24)

    float* ws = (float*)d_ws;
    ushort_t* s1m16 = (ushort_t*)(ws + 0);         // 555025 u16 (pad to 277520 floats)
    ushort_t* ivm16 = (ushort_t*)(ws + 277520);    // 555025 u16
    float*    mx    = ws + 555040;                 // 256
    ushort_t* Bmat  = (ushort_t*)(ws + 555296);    // 442368 u16 (16B-aligned)
    int*      cand  = (int*)(ws + 776480);         // 2048
    ushort_t* ps16  = (ushort_t*)(ws + 778528);    // 1,148,928 u16 [blk][pat]
    ushort_t* y2    = (ushort_t*)(ws + 1352992);   // 3,538,944 u16 (16B-aligned)
    // box-sum temps alias ps16+y2 region (dead before k_y2/k_corr):
    float* ksum  = ws + 778528;                    // 589824
    float* ksum2 = ws + 1368352;                   // 589824
    float* h1    = ws + 1958176;                   // 572160
    float* h2    = ws + 2530336;                   // 572160 (end 3,102,496 < 3,124,512)

    k_colsum<<<(HH * WW + 255) / 256, 256, 0, stream>>>(ydec, ksum, ksum2);
    k_hsum<<<(HH * WC + 255) / 256, 256, 0, stream>>>(ksum, ksum2, h1, h2);
    k_vsum<<<(HC * WC + 255) / 256, 256, 0, stream>>>(h1, h2, s1m16, ivm16);
    k_meanx<<<NP, 256, 0, stream>>>(xdec, mx);
    k_bmat<<<NP, 256, 0, stream>>>(xdec, Bmat);
    k_y2<<<(2 * 3 * HH * (WW / 8) + 255) / 256, 256, 0, stream>>>(ydec, y2);

    k_corr<<<NBLK, 512, 0, stream>>>(y2, Bmat, s1m16, ivm16, mx, ps16);
    k_select<<<NP, 256, 0, stream>>>(ps16, cand);
    k_rescore<<<NP, 256, 0, stream>>>(cand, xdec, ydec, mx, y, out);
}

// Round 7
// 944.804 us; speedup vs baseline: 1.0509x; 1.0509x over previous
//
#include <hip/hip_runtime.h>

typedef __bf16 bf16x8 __attribute__((ext_vector_type(8)));
typedef float  v16f   __attribute__((ext_vector_type(16)));
typedef unsigned short ushort_t;

#define HH 768
#define WW 768
#define CH 3
#define KS 24
#define HC 745
#define WC 745
#define NP 256
#define XH 384
#define XW 384

#define NBX 24            // ceil(745/32)
#define NBY 187           // ceil(745/4)
#define NBLK (NBX*NBY)    // 4488
#define BROWS 4
#define BCOLS 32
#define NSTEP 54          // K=1728 in 32-wide slices
#define NCAND 8

// async global->LDS DMA; LDS dest = wave-uniform base + lane*size (global addr is per-lane)
__device__ __forceinline__ void gload16(const ushort_t* g, ushort_t* l) {
    __builtin_amdgcn_global_load_lds(
        (const __attribute__((address_space(1))) unsigned int*)(const void*)g,
        (__attribute__((address_space(3))) unsigned int*)(void*)l, 16, 0, 0);
}
__device__ __forceinline__ void gload4(const ushort_t* g, ushort_t* l) {
    __builtin_amdgcn_global_load_lds(
        (const __attribute__((address_space(1))) unsigned int*)(const void*)g,
        (__attribute__((address_space(3))) unsigned int*)(void*)l, 4, 0, 0);
}
__device__ __forceinline__ ushort_t f2bf(float f) {
    union { __bf16 h; ushort_t u; } cv; cv.h = (__bf16)f; return cv.u;
}
__device__ __forceinline__ float bf2f(ushort_t u) {
    union { unsigned u; float f; } cv; cv.u = ((unsigned)u) << 16; return cv.f;
}

// -------------------- prep kernels --------------------

__global__ void k_colsum(const float* __restrict__ y, float* __restrict__ ksum,
                         float* __restrict__ ksum2) {
    int idx = blockIdx.x * 256 + threadIdx.x;
    if (idx >= HH * WW) return;
    float a = y[idx], b = y[idx + HH * WW], c = y[idx + 2 * HH * WW];
    ksum[idx]  = a + b + c;
    ksum2[idx] = a * a + b * b + c * c;
}

__global__ void k_hsum(const float* __restrict__ ksum, const float* __restrict__ ksum2,
                       float* __restrict__ h1, float* __restrict__ h2) {
    int idx = blockIdx.x * 256 + threadIdx.x;
    if (idx >= HH * WC) return;
    int h = idx / WC, w = idx % WC;
    const float* r  = ksum  + h * WW + w;
    const float* r2 = ksum2 + h * WW + w;
    float s = 0.f, s2 = 0.f;
    #pragma unroll
    for (int j = 0; j < KS; j++) { s += r[j]; s2 += r2[j]; }
    h1[idx] = s; h2[idx] = s2;
}

// bf16 maps are ONLY used for the approximate pre-screen; k_rescore recomputes exactly.
__global__ void k_vsum(const float* __restrict__ h1, const float* __restrict__ h2,
                       ushort_t* __restrict__ s1m, ushort_t* __restrict__ ivm) {
    int idx = blockIdx.x * 256 + threadIdx.x;
    if (idx >= HC * WC) return;
    int r = idx / WC, w = idx % WC;
    float s = 0.f, s2 = 0.f;
    #pragma unroll
    for (int i = 0; i < KS; i++) { s += h1[(r + i) * WC + w]; s2 += h2[(r + i) * WC + w]; }
    float d2 = s2 - s * s * (1.0f / 576.0f);
    s1m[idx] = f2bf(s);
    ivm[idx] = f2bf(rsqrtf(fmaxf(d2, 1e-20f)));
}

__global__ void k_meanx(const float* __restrict__ x, float* __restrict__ mx) {
    int p = blockIdx.x;
    int pr = p >> 4, pc = p & 15;
    float s = 0.f;
    for (int e = threadIdx.x; e < CH * KS * KS; e += 256) {
        int c = e / (KS * KS); int rem = e % (KS * KS);
        int i = rem / KS, j = rem % KS;
        s += x[(c * XH + pr * KS + i) * XW + pc * KS + j];
    }
    __shared__ float red[256];
    red[threadIdx.x] = s; __syncthreads();
    for (int st = 128; st > 0; st >>= 1) {
        if (threadIdx.x < st) red[threadIdx.x] += red[threadIdx.x + st];
        __syncthreads();
    }
    if (threadIdx.x == 0) mx[p] = red[0] * (1.0f / 1728.0f);
}

__global__ void k_bmat(const float* __restrict__ x, ushort_t* __restrict__ bm) {
    int p = blockIdx.x; int pr = p >> 4, pc = p & 15;
    for (int e = threadIdx.x; e < CH * KS * KS; e += 256) {
        int c = e / (KS * KS), rem = e % (KS * KS), i = rem / KS, j = rem % KS;
        bm[p * 1728 + e] = f2bf(x[(c * XH + pr * KS + i) * XW + pc * KS + j]);
    }
}

// 2 column-shifted bf16 copies: y2[S][c][r][t] = bf16(ydec[c][r][t+S]), S in {0,1}, 0-pad OOB.
__global__ void k_y2(const float* __restrict__ yd, ushort_t* __restrict__ y2) {
    int idx = blockIdx.x * 256 + threadIdx.x;
    if (idx >= 2 * 3 * HH * (WW / 8)) return;
    int t8 = idx % (WW / 8); int rem = idx / (WW / 8);
    int r = rem % HH; rem /= HH;
    int c = rem % 3; int S = rem / 3;
    const float* src = yd + (c * HH + r) * WW;
    union { ushort_t u[8]; uint4 v; } o;
    #pragma unroll
    for (int q = 0; q < 8; q++) {
        int t = t8 * 8 + q + S;
        o.u[q] = f2bf(t < WW ? src[t] : 0.f);
    }
    ((uint4*)(y2 + ((size_t)(S * 3 + c) * HH + r) * WW))[t8] = o.v;
}

// -------------------- main MFMA correlation kernel --------------------
// 256 thr (4 waves), grid (NBLK, 2): tile = 128 pos (4x32) x 128 patches; wave tile 64x64
// of mfma_f32_32x32x16_bf16. Slot-major LDS [k-octet-plane][row][8] (conflict-free, R6).
// Staging: fixed per-thread offset + scalar-advancing base (SALU only); no clamps — OOB
// reads touch only masked-invalid positions and stay within the proven ws footprint.

__global__ __launch_bounds__(256, 4) void k_corr(
    const ushort_t* __restrict__ y2, const ushort_t* __restrict__ bmat,
    const ushort_t* __restrict__ s1m, const ushort_t* __restrict__ ivm,
    const float* __restrict__ mx, ushort_t* __restrict__ ps16)
{
    __shared__ __align__(16) ushort_t Ab[4 * 128 * 8];   // 8KB [oct][pos][8]
    __shared__ __align__(16) ushort_t Bb[4 * 128 * 8];   // 8KB [oct][pat][8]
    __shared__ float red[128 * 2];

    const int tid = threadIdx.x;
    const int wave = tid >> 6, lane = tid & 63;
    const int bx = blockIdx.x % NBX, by = blockIdx.x / NBX;
    const int r0 = by * BROWS, w0 = bx * BCOLS;
    const int zbase = blockIdx.y * 128;                  // patch half

    // ---- A staging constants: round (u,h2): dest byte = u*2048 + h2*1024 + 4*tid ----
    // pos = h2*64 + (tid>>2), dword (k-pair) = tid&3; parity-matched shifted copy per thread.
    const int pos0 = tid >> 2, dword = tid & 3;
    int a_toff[2];
    #pragma unroll
    for (int h2 = 0; h2 < 2; h2++) {
        int pos = h2 * 64 + pos0;
        int prow = pos >> 5, pcol = pos & 31;
        int Sp = pcol & 1;                               // w0 even, octet col-offset even
        a_toff[h2] = Sp * (3 * HH * WW) + prow * WW + pcol - Sp + dword * 2;
    }
    ushort_t* adst = Ab + wave * 128;                    // + u*1024 + h2*512 (wave-uniform)

    // ---- B staging: round q: dest byte = q*4096 + wave*1024 + 16*lane ----
    // -> plane q*2 + (wave>>1), pat-row (wave&1)*64 + lane
    const int b_toff = (zbase + (wave & 1) * 64 + lane) * 1728 + (wave >> 1) * 8;
    ushort_t* bdst = Bb + wave * 512;                    // + q*2048
    const ushort_t* bbase = bmat;                        // += 32 per slice

    const int l31 = lane & 31, h = lane >> 5;
    const int wm = wave >> 1, wn = wave & 1;

    v16f acc[2][2];
    #pragma unroll
    for (int a = 0; a < 2; a++)
        #pragma unroll
        for (int b = 0; b < 2; b++)
            #pragma unroll
            for (int r = 0; r < 16; r++) acc[a][b][r] = 0.f;

    const ushort_t* abase = y2 + (size_t)r0 * WW + w0;   // octet (c=0,i=0,jj=0)
    int jc = 0, ic = 0;                                  // uniform octet cursor (SALU)

    #pragma unroll 1
    for (int s = 0; s < NSTEP; s++) {
        __syncthreads();                                 // old tiles fully consumed
        #pragma unroll
        for (int u = 0; u < 4; u++) {                    // A octets first (scattered, slower)
            gload4(abase + a_toff[0], adst + u * 1024);
            gload4(abase + a_toff[1], adst + u * 1024 + 512);
            abase += 8;
            if (++jc == 3) {
                jc = 0; abase += WW - 24;
                if (++ic == 24) { ic = 0; abase += (size_t)(HH - 24) * WW; }
            }
        }
        gload16(bbase + b_toff,      bdst);              // B octets (L2-hot)
        gload16(bbase + b_toff + 16, bdst + 2048);
        bbase += 32;
        __syncthreads();                                 // staging landed

        bf16x8 af[2][2], bfr[2][2];
        #pragma unroll
        for (int mt = 0; mt < 2; mt++)
            #pragma unroll
            for (int ks = 0; ks < 2; ks++)
                af[mt][ks] = *(const bf16x8*)(Ab + (ks * 2 + h) * 1024 + (wm * 64 + mt * 32 + l31) * 8);
        #pragma unroll
        for (int nt = 0; nt < 2; nt++)
            #pragma unroll
            for (int ks = 0; ks < 2; ks++)
                bfr[nt][ks] = *(const bf16x8*)(Bb + (ks * 2 + h) * 1024 + (wn * 64 + nt * 32 + l31) * 8);
        #pragma unroll
        for (int ks = 0; ks < 2; ks++)
            #pragma unroll
            for (int mt = 0; mt < 2; mt++)
                #pragma unroll
                for (int nt = 0; nt < 2; nt++)
                    acc[mt][nt] = __builtin_amdgcn_mfma_f32_32x32x16_bf16(
                        af[mt][ks], bfr[nt][ks], acc[mt][nt], 0, 0, 0);
    }

    // epilogue: approx score + per-(patch, block) max
    float mx0 = mx[zbase + wn * 64 + l31];
    float mx1 = mx[zbase + wn * 64 + 32 + l31];
    float best0 = -1e30f, best1 = -1e30f;
    #pragma unroll
    for (int mt = 0; mt < 2; mt++) {
        #pragma unroll
        for (int r = 0; r < 16; r++) {
            int row32 = (r & 3) + 8 * (r >> 2) + 4 * h;   // 32x32 C/D row (m74/m101)
            int posid = wm * 64 + mt * 32 + row32;
            int rg = r0 + (posid >> 5), wg = w0 + (posid & 31);
            bool valid = (rg < HC) && (wg < WC);
            int pos = rg * WC + wg;
            float S1 = valid ? bf2f(s1m[pos]) : 0.f;
            float iv = valid ? bf2f(ivm[pos]) : 0.f;
            float sc0 = valid ? (acc[mt][0][r] - mx0 * S1) * iv : -1e30f;
            float sc1 = valid ? (acc[mt][1][r] - mx1 * S1) * iv : -1e30f;
            best0 = fmaxf(best0, sc0);
            best1 = fmaxf(best1, sc1);
        }
    }
    best0 = fmaxf(best0, __shfl_xor(best0, 32));         // reduce over h
    best1 = fmaxf(best1, __shfl_xor(best1, 32));
    __syncthreads();
    if (h == 0) {
        red[(wn * 64 + l31) * 2 + wm]      = best0;
        red[(wn * 64 + 32 + l31) * 2 + wm] = best1;
    }
    __syncthreads();
    if (tid < 128)
        ps16[blockIdx.x * NP + zbase + tid] = f2bf(fmaxf(red[tid * 2], red[tid * 2 + 1]));
}

// -------------------- per-patch top-8 blocks --------------------

__global__ void k_select(const ushort_t* __restrict__ ps16, int* __restrict__ cand) {
    int p = blockIdx.x, tid = threadIdx.x;
    __shared__ float ls[NBLK];
    __shared__ float rs[256];
    __shared__ int   ri[256];
    for (int e = tid; e < NBLK; e += 256) ls[e] = bf2f(ps16[e * NP + p]);
    __syncthreads();
    for (int round = 0; round < NCAND; round++) {
        float bs = -1e38f; int bi = 0;
        for (int e = tid; e < NBLK; e += 256) if (ls[e] > bs) { bs = ls[e]; bi = e; }
        rs[tid] = bs; ri[tid] = bi; __syncthreads();
        for (int st = 128; st > 0; st >>= 1) {
            if (tid < st && rs[tid + st] > rs[tid]) { rs[tid] = rs[tid + st]; ri[tid] = ri[tid + st]; }
            __syncthreads();
        }
        int win = ri[0];
        if (tid == 0) cand[p * NCAND + round] = win;
        if (tid == (win & 255)) ls[win] = -1e38f;
        __syncthreads();
    }
}

// -------------------- exact fp32 rescore (recomputes window sums) + gather --------------------

__global__ void k_rescore(const int* __restrict__ cand, const float* __restrict__ xdec,
                          const float* __restrict__ ydec, const float* __restrict__ mx,
                          const float* __restrict__ yfull, float* __restrict__ out) {
    int p = blockIdx.x, tid = threadIdx.x;
    int pr = p >> 4, pc = p & 15;
    float mxp = mx[p];
    float best = -1e30f; int bpos = 0x7FFFFFFF;
    #pragma unroll 1
    for (int cdp = 0; cdp < 4; cdp++) {
        int cd = cdp * 2 + (tid >> 7);
        int blk = cand[p * NCAND + cd];
        int r0 = (blk / NBX) * BROWS, w0 = (blk % NBX) * BCOLS;
        int pi = tid & 127;
        int rg = r0 + (pi >> 5), wg = w0 + (pi & 31);
        if (rg < HC && wg < WC) {
            float sxy = 0.f, sy = 0.f, sy2 = 0.f;
            for (int c = 0; c < CH; c++) {
                #pragma unroll 1
                for (int i = 0; i < KS; i++) {
                    const float* yr = ydec + (c * HH + rg + i) * WW + wg;
                    const float* xr = xdec + (c * XH + pr * KS + i) * XW + pc * KS;
                    #pragma unroll
                    for (int j = 0; j < KS; j++) {
                        float yv = yr[j];
                        sxy = fmaf(yv, xr[j], sxy);
                        sy += yv;
                        sy2 = fmaf(yv, yv, sy2);
                    }
                }
            }
            float d2 = sy2 - sy * sy * (1.0f / 576.0f);
            int pos = rg * WC + wg;
            float sc = (sxy - mxp * sy) * rsqrtf(fmaxf(d2, 1e-20f));
            if (sc > best || (sc == best && pos < bpos)) { best = sc; bpos = pos; }
        }
    }
    __shared__ float rs[256];
    __shared__ int   ri[256];
    rs[tid] = best; ri[tid] = bpos; __syncthreads();
    for (int st = 128; st > 0; st >>= 1) {
        if (tid < st) {
            if (rs[tid + st] > rs[tid] || (rs[tid + st] == rs[tid] && ri[tid + st] < ri[tid])) {
                rs[tid] = rs[tid + st]; ri[tid] = ri[tid + st];
            }
        }
        __syncthreads();
    }
    int bestpos = ri[0];
    int row = bestpos / WC, col = bestpos % WC;
    for (int e = tid; e < CH * KS * KS; e += 256) {
        int c = e / (KS * KS), rem = e % (KS * KS), i = rem / KS, j = rem % KS;
        out[p * CH * KS * KS + e] = yfull[(c * HH + row + i) * WW + col + j];
    }
}

// -------------------- launch --------------------
// ws high-water: writes to 3,122,464 floats (11.9 MB); transient OOB *reads* reach
// ~3,123,700 floats (12.49 MB) — safely under the >=13.7 MB proven by R1-R3.

extern "C" void kernel_launch(void* const* d_in, const int* in_sizes, int n_in,
                              void* d_out, int out_size, void* d_ws, size_t ws_size,
                              hipStream_t stream) {
    const float* xdec = (const float*)d_in[0];   // (1,3,384,384)
    const float* ydec = (const float*)d_in[1];   // (1,3,768,768)
    const float* y    = (const float*)d_in[2];   // (1,3,768,768)
    float* out = (float*)d_out;                  // (256,3,24,24)

    float* ws = (float*)d_ws;
    ushort_t* s1m16 = (ushort_t*)(ws + 0);         // 555025 u16 (pad to 277520 floats)
    ushort_t* ivm16 = (ushort_t*)(ws + 277520);    // 555025 u16
    float*    mx    = ws + 555040;                 // 256
    ushort_t* Bmat  = (ushort_t*)(ws + 555296);    // 442368 u16 (16B-aligned)
    int*      cand  = (int*)(ws + 776480);         // 2048
    ushort_t* ps16  = (ushort_t*)(ws + 778528);    // 1,148,928 u16 [blk][pat]
    ushort_t* y2    = (ushort_t*)(ws + 1352992);   // 3,538,944 u16 (16B-aligned)
    // box-sum temps alias ps16+y2 region (dead before k_y2/k_corr):
    float* ksum  = ws + 778528;                    // 589824
    float* ksum2 = ws + 1368352;                   // 589824
    float* h1    = ws + 1958176;                   // 572160
    float* h2    = ws + 2530336;                   // 572160 (end 3,102,496)

    k_colsum<<<(HH * WW + 255) / 256, 256, 0, stream>>>(ydec, ksum, ksum2);
    k_hsum<<<(HH * WC + 255) / 256, 256, 0, stream>>>(ksum, ksum2, h1, h2);
    k_vsum<<<(HC * WC + 255) / 256, 256, 0, stream>>>(h1, h2, s1m16, ivm16);
    k_meanx<<<NP, 256, 0, stream>>>(xdec, mx);
    k_bmat<<<NP, 256, 0, stream>>>(xdec, Bmat);
    k_y2<<<(2 * 3 * HH * (WW / 8) + 255) / 256, 256, 0, stream>>>(ydec, y2);

    dim3 grid(NBLK, 2);
    k_corr<<<grid, 256, 0, stream>>>(y2, Bmat, s1m16, ivm16, mx, ps16);
    k_select<<<NP, 256, 0, stream>>>(ps16, cand);
    k_rescore<<<NP, 256, 0, stream>>>(cand, xdec, ydec, mx, y, out);
}